// Round 3
// baseline (3821.885 us; speedup 1.0000x reference)
//
#include <hip/hip_runtime.h>
#include <stdint.h>

#define T_LEN 2048
#define L     1024
#define NFB   64            // blocks per chain
#define GOLDB 128           // legacy mitm gold block id
#define CPB   16            // columns (rows) per block; 4 per wave
#define TPB   256
#define TMID  1023          // forward computes f_{1023}; backward computes b_{1023}
#define BSTEPS 1024         // backward step count (s=1..1024, emission row t=2048-s)
#define SPIN_MAX (1 << 14)  // bounded; mixed loop uses proven agent loads -> no wedge
#define V3_GRID 512         // fwd = bid%8==0, bwd = bid%8==1, gold = bid 2, rest exit
#define FASTK0  24          // sc0 fast-poll iterations before falling to mixed loop

#define SCOPE_AGENT __HIP_MEMORY_SCOPE_AGENT
#define LDA(p) __hip_atomic_load((p), __ATOMIC_RELAXED, SCOPE_AGENT)
#define STA(p, v) __hip_atomic_store((p), (v), __ATOMIC_RELAXED, SCOPE_AGENT)

__device__ __forceinline__ uint64_t pack_su(int tag, float v) {
    return ((uint64_t)(uint32_t)tag << 32) | (uint64_t)__float_as_uint(v);
}

// ---------------------------------------------------------------------
// Scoped memory ops. sc0 = local-L2-coherent (fast, placement-dependent);
// sc1 = device/agent scope (proven-correct baseline path). Every published
// value goes to BOTH a sc0 buffer and an agent buffer; readers satisfy each
// tagged slot from whichever copy shows tag >= expect. Correct regardless
// of sc0 semantics or block->XCD placement.
// ---------------------------------------------------------------------
static __device__ __forceinline__ void ld2_sc0(const uint64_t* p, uint64_t& v) {
    asm volatile("global_load_dwordx2 %0, %1, off sc0" : "=v"(v) : "v"(p) : "memory");
}
static __device__ __forceinline__ void ld2_agent(const uint64_t* p, uint64_t& v) {
    asm volatile("global_load_dwordx2 %0, %1, off sc1" : "=v"(v) : "v"(p) : "memory");
}
static __device__ __forceinline__ void st2_sc0(uint64_t* p, uint64_t v) {
    asm volatile("global_store_dwordx2 %0, %1, off sc0" : : "v"(p), "v"(v) : "memory");
}
static __device__ __forceinline__ void st2_agent(uint64_t* p, uint64_t v) {
    asm volatile("global_store_dwordx2 %0, %1, off sc1" : : "v"(p), "v"(v) : "memory");
}
static __device__ __forceinline__ void vm0_fence() {
    // rule 18: asm waitcnt needs a sched_barrier so register-only tag checks
    // cannot be hoisted above the wait.
    asm volatile("s_waitcnt vmcnt(0)" ::: "memory");
    __builtin_amdgcn_sched_barrier(0);
}

// Poll this thread's 4 slots. Fast phase: sc0 only (~local-L2 latency).
// Mixed phase: sc0 + agent copies; each slot satisfied by either copy.
// fastK self-kills (per-thread) if the fast phase fails after warm-up.
static __device__ __forceinline__ void poll4_dual(
    const uint64_t* __restrict__ px, const uint64_t* __restrict__ pa,
    const int expect, int& fastK,
    uint64_t& o0, uint64_t& o1, uint64_t& o2, uint64_t& o3)
{
    int have = 0;
    uint64_t x0, x1, x2, x3;
    for (int i = 0; i < fastK; ++i) {
        ld2_sc0(px + 0, x0); ld2_sc0(px + 1, x1);
        ld2_sc0(px + 2, x2); ld2_sc0(px + 3, x3);
        vm0_fence();
        if (!(have & 1) && (int)(x0 >> 32) >= expect) { o0 = x0; have |= 1; }
        if (!(have & 2) && (int)(x1 >> 32) >= expect) { o1 = x1; have |= 2; }
        if (!(have & 4) && (int)(x2 >> 32) >= expect) { o2 = x2; have |= 4; }
        if (!(have & 8) && (int)(x3 >> 32) >= expect) { o3 = x3; have |= 8; }
        if (have == 15) return;
    }
    if (expect >= 8) fastK = 0;     // past warm-up: sc0 path ineffective, stop paying
    int n = 0;
    uint64_t a0, a1, a2, a3;
    for (;;) {
        ld2_sc0(px + 0, x0); ld2_sc0(px + 1, x1);
        ld2_sc0(px + 2, x2); ld2_sc0(px + 3, x3);
        ld2_agent(pa + 0, a0); ld2_agent(pa + 1, a1);
        ld2_agent(pa + 2, a2); ld2_agent(pa + 3, a3);
        vm0_fence();
        if (!(have & 1)) { if ((int)(x0 >> 32) >= expect) { o0 = x0; have |= 1; }
                           else if ((int)(a0 >> 32) >= expect) { o0 = a0; have |= 1; } }
        if (!(have & 2)) { if ((int)(x1 >> 32) >= expect) { o1 = x1; have |= 2; }
                           else if ((int)(a1 >> 32) >= expect) { o1 = a1; have |= 2; } }
        if (!(have & 4)) { if ((int)(x2 >> 32) >= expect) { o2 = x2; have |= 4; }
                           else if ((int)(a2 >> 32) >= expect) { o2 = a2; have |= 4; } }
        if (!(have & 8)) { if ((int)(x3 >> 32) >= expect) { o3 = x3; have |= 8; }
                           else if ((int)(a3 >> 32) >= expect) { o3 = a3; have |= 8; } }
        if (have == 15 || ++n >= SPIN_MAX) return;
        if (n >= 64) __builtin_amdgcn_s_sleep(1);
    }
}

// =====================================================================
// v3: dual-published meet-in-the-middle.
//   Static roles: bid%8==0 -> forward role bid/8 (XCD 0 under round-robin),
//   bid%8==1 -> backward role bid/8 (XCD 1), bid==2 -> gold, rest exit.
//   All 128 chain blocks exist unconditionally and co-reside -> no
//   placement machinery, no structural deadlock. Handoff values are
//   dual-published (sc0 + agent buffers); readers poll sc0 fast, fall
//   back to the proven agent path per-slot. Block-local exp-shift
//   (own previous value) removes the cross-block shift coupling.
// ws layout (u64): fbX0 fbX1 bbX0 bbX1 | fbA0 fbA1 bbA0 bbA1 (L each) | gold
// Requires ws >= (8*L + 1) * 8 = 65544 bytes.
// =====================================================================
__global__ __launch_bounds__(TPB, 1)
void crf_v3(const float* __restrict__ feats,
            const float* __restrict__ transfer,
            const int* __restrict__ target,
            float* __restrict__ out,
            uint64_t* __restrict__ ws64)
{
    __shared__ __align__(16) float qbuf[2][L];      // 8 KB, double-buffered
    __shared__ float red[8];
    __shared__ float sh_shift;                      // block-local exp shift

    uint64_t* fbX0 = ws64;                          // sc0 copies
    uint64_t* fbX1 = ws64 + L;
    uint64_t* bbX0 = ws64 + 2 * L;
    uint64_t* bbX1 = ws64 + 3 * L;
    uint64_t* fbA0 = ws64 + 4 * L;                  // agent copies (ground truth)
    uint64_t* fbA1 = ws64 + 5 * L;
    uint64_t* bbA0 = ws64 + 6 * L;
    uint64_t* bbA1 = ws64 + 7 * L;
    uint64_t* goldslot = ws64 + 8 * L;

    const int bid  = blockIdx.x;
    const int tid  = threadIdx.x;
    const int lane = tid & 63;
    const int wv   = tid >> 6;                      // wave 0..3
    const int cl   = 2 * (lane & 1) + ((lane >> 1) & 1);   // bijective on lanes 0..3

    // ---------------- gold block ----------------
    if (bid == 2) {
        float s = 0.f;
        for (int t = tid; t < T_LEN; t += TPB)
            s += feats[t * L + target[t]];
        for (int t = tid; t < T_LEN - 1; t += TPB)
            s += transfer[target[t] * L + target[t + 1]];
        #pragma unroll
        for (int m = 32; m; m >>= 1) s += __shfl_xor(s, m, 64);
        if (lane == 0) red[wv] = s;
        __syncthreads();
        if (tid == 0) {
            float g = red[0] + red[1] + red[2] + red[3];
            STA(goldslot, pack_su(1, g));
        }
        return;
    }

    const int sel  = bid & 7;
    const int role = bid >> 3;                      // 0..63
    if (sel >= 2) return;                           // idle filler blocks

    if (sel == 0) {
        // ================= FORWARD chain (1023 steps) =================
        const int gcb    = role * CPB + 4 * wv;     // wave's first global column
        const int shslot = role * CPB;

        float E[16][4];                             // E[k][c]=exp(transfer[lane+64k][gcb+c])
        #pragma unroll
        for (int k = 0; k < 16; ++k) {
            const float4 r = *(const float4*)(transfer + (size_t)(lane + 64 * k) * L + gcb);
            E[k][0] = __expf(r.x); E[k][1] = __expf(r.y);
            E[k][2] = __expf(r.z); E[k][3] = __expf(r.w);
        }

        // Seed OWN slots (same thread that will later write them -> same-address
        // program order; vmcnt(0) drain below makes it airtight) with tag -1.
        if (lane < 4) {
            const uint64_t sv = pack_su(-1, 0.f);
            st2_sc0(&fbX0[gcb + cl], sv); st2_sc0(&fbX1[gcb + cl], sv);
            st2_agent(&fbA0[gcb + cl], sv); st2_agent(&fbA1[gcb + cl], sv);
        }
        asm volatile("s_waitcnt vmcnt(0)" ::: "memory");
        __syncthreads();

        int fastK = FASTK0;
        for (int t = 1; t <= TMID; ++t) {
            const int par = t & 1;
            uint64_t* rX = par ? fbX0 : fbX1;
            const uint64_t* rA = par ? fbA0 : fbA1;
            uint64_t* wX = par ? fbX1 : fbX0;
            uint64_t* wA = par ? fbA1 : fbA0;
            const int expect = t - 1;

            const float fe = feats[(size_t)t * L + gcb + cl];   // overlaps poll

            float p0, p1, p2, p3, sloc;
            if (t == 1) {
                // f_0 = feats[0] read directly: no ws poll at step 1
                const float4 pv = *(const float4*)(feats + 4 * tid);
                p0 = pv.x; p1 = pv.y; p2 = pv.z; p3 = pv.w;
                sloc = feats[shslot];
            } else {
                sloc = sh_shift;                    // own previous value (post-barrier)
                uint64_t v0, v1, v2, v3;
                poll4_dual(rX + 4 * tid, rA + 4 * tid, expect, fastK, v0, v1, v2, v3);
                p0 = __uint_as_float((uint32_t)v0);
                p1 = __uint_as_float((uint32_t)v1);
                p2 = __uint_as_float((uint32_t)v2);
                p3 = __uint_as_float((uint32_t)v3);
            }

            float* qb = qbuf[par];
            float4 qv;
            qv.x = __expf(p0 - sloc);
            qv.y = __expf(p1 - sloc);
            qv.z = __expf(p2 - sloc);
            qv.w = __expf(p3 - sloc);
            ((float4*)qb)[tid] = qv;
            __syncthreads();

            float a0 = 0.f, a1 = 0.f, a2 = 0.f, a3 = 0.f;
            #pragma unroll
            for (int k = 0; k < 16; ++k) {
                const float q = qb[lane + 64 * k];   // conflict-free ds_read_b32
                a0 += q * E[k][0]; a1 += q * E[k][1];
                a2 += q * E[k][2]; a3 += q * E[k][3];
            }

            {   // split-reduction: 4 accs -> 1 per lane (col = cl)
                const bool h1 = lane & 1;
                float s0 = h1 ? a0 : a2;  float r0 = __shfl_xor(s0, 1, 64);
                float s1 = h1 ? a1 : a3;  float r1 = __shfl_xor(s1, 1, 64);
                a0 = (h1 ? a2 : a0) + r0;
                a1 = (h1 ? a3 : a1) + r1;
                const bool h2 = lane & 2;
                float s2 = h2 ? a0 : a1;  float r2 = __shfl_xor(s2, 2, 64);
                a0 = (h2 ? a1 : a0) + r2;
            }
            float s = a0;
            s += __shfl_xor(s, 4, 64);
            s += __shfl_xor(s, 8, 64);
            s += __shfl_xor(s, 16, 64);
            s += __shfl_xor(s, 32, 64);

            const float nv = sloc + __logf(s) + fe;
            if (lane < 4) {
                const uint64_t pv2 = pack_su(t, nv);
                st2_sc0(&wX[gcb + cl], pv2);
                st2_agent(&wA[gcb + cl], pv2);
            }
            if (tid == 0) sh_shift = nv;            // tid0: cl==0 -> col role*CPB
            __syncthreads();
        }

        // ---------- role 0: logZ = lse(f_{1023} + b_{1023}) - gold ----------
        if (role == 0) {
            const uint64_t* fp = fbA1 + 4 * tid;    // t=1023 odd -> A-copy parity 1
            const uint64_t* bp = bbA0 + 4 * tid;    // s=1024 even -> A-copy parity 0
            uint64_t f0, f1, f2, f3, g0, g1, g2, g3;
            int n = 0;
            for (;;) {
                f0 = LDA(fp + 0); f1 = LDA(fp + 1); f2 = LDA(fp + 2); f3 = LDA(fp + 3);
                g0 = LDA(bp + 0); g1 = LDA(bp + 1); g2 = LDA(bp + 2); g3 = LDA(bp + 3);
                bool ready = ((int)(f0 >> 32) >= TMID) & ((int)(f1 >> 32) >= TMID) &
                             ((int)(f2 >> 32) >= TMID) & ((int)(f3 >> 32) >= TMID) &
                             ((int)(g0 >> 32) >= BSTEPS) & ((int)(g1 >> 32) >= BSTEPS) &
                             ((int)(g2 >> 32) >= BSTEPS) & ((int)(g3 >> 32) >= BSTEPS);
                if (ready || ++n >= SPIN_MAX) break;
                if (n >= 64) __builtin_amdgcn_s_sleep(1);
            }
            float sv[4] = {
                __uint_as_float((uint32_t)f0) + __uint_as_float((uint32_t)g0),
                __uint_as_float((uint32_t)f1) + __uint_as_float((uint32_t)g1),
                __uint_as_float((uint32_t)f2) + __uint_as_float((uint32_t)g2),
                __uint_as_float((uint32_t)f3) + __uint_as_float((uint32_t)g3) };
            float mx = fmaxf(fmaxf(sv[0], sv[1]), fmaxf(sv[2], sv[3]));
            #pragma unroll
            for (int m = 32; m; m >>= 1) mx = fmaxf(mx, __shfl_xor(mx, m, 64));
            if (lane == 0) red[wv] = mx;
            __syncthreads();
            const float M = fmaxf(fmaxf(red[0], red[1]), fmaxf(red[2], red[3]));
            float sm = 0.f;
            #pragma unroll
            for (int k = 0; k < 4; ++k) sm += __expf(sv[k] - M);
            #pragma unroll
            for (int m = 32; m; m >>= 1) sm += __shfl_xor(sm, m, 64);
            if (lane == 0) red[4 + wv] = sm;
            __syncthreads();
            if (tid == 0) {
                const float S = red[4] + red[5] + red[6] + red[7];
                const float lse = M + __logf(S);
                uint64_t g = LDA(goldslot);
                int n2 = 0;
                while ((int)(g >> 32) < 1 && ++n2 < SPIN_MAX) g = LDA(goldslot);
                out[0] = lse - __uint_as_float((uint32_t)g);
            }
        }
        return;
    }

    // ================= BACKWARD chain (1024 steps) =================
    {
        const int rowbase = role * CPB + 4 * wv;    // wave's first global row

        // E[k][r] = exp(transfer[(rowbase+r)*L + lane+64k]) — coalesced staging
        float E[16][4];
        #pragma unroll
        for (int r = 0; r < 4; ++r) {
            const float* rowp = transfer + (size_t)(rowbase + r) * L + lane;
            #pragma unroll
            for (int k = 0; k < 16; ++k)
                E[k][r] = __expf(rowp[64 * k]);
        }

        if (lane < 4) {                             // seed own slots, tag -1
            const uint64_t sv = pack_su(-1, 0.f);
            st2_sc0(&bbX0[rowbase + cl], sv); st2_sc0(&bbX1[rowbase + cl], sv);
            st2_agent(&bbA0[rowbase + cl], sv); st2_agent(&bbA1[rowbase + cl], sv);
        }
        asm volatile("s_waitcnt vmcnt(0)" ::: "memory");
        __syncthreads();

        int fastK = FASTK0;
        for (int s = 1; s <= BSTEPS; ++s) {
            const int par = s & 1;
            uint64_t* rX = par ? bbX0 : bbX1;
            const uint64_t* rA = par ? bbA0 : bbA1;
            uint64_t* wX = par ? bbX1 : bbX0;
            uint64_t* wA = par ? bbA1 : bbA0;
            const int expect = s - 1;
            const int t = T_LEN - s;                // emission row for this step

            // prefetch emission chunk for my 4 j's (overlaps poll)
            const float4 fv = *(const float4*)(feats + (size_t)t * L + 4 * tid);

            float b0, b1, b2, b3, sb;
            if (s == 1) {
                b0 = 0.f; b1 = 0.f; b2 = 0.f; b3 = 0.f; sb = 0.f;   // b_{2047}=0
            } else {
                sb = sh_shift;
                uint64_t v0, v1, v2, v3;
                poll4_dual(rX + 4 * tid, rA + 4 * tid, expect, fastK, v0, v1, v2, v3);
                b0 = __uint_as_float((uint32_t)v0);
                b1 = __uint_as_float((uint32_t)v1);
                b2 = __uint_as_float((uint32_t)v2);
                b3 = __uint_as_float((uint32_t)v3);
            }

            // w_j = exp(feats[t][j] + b[j] - sb) -> LDS broadcast
            float* qb = qbuf[par];
            float4 wv4;
            wv4.x = __expf(fv.x + b0 - sb);
            wv4.y = __expf(fv.y + b1 - sb);
            wv4.z = __expf(fv.z + b2 - sb);
            wv4.w = __expf(fv.w + b3 - sb);
            ((float4*)qb)[tid] = wv4;
            __syncthreads();

            // matvec: acc[r] += w[lane+64k] * E[k][r]
            float a0 = 0.f, a1 = 0.f, a2 = 0.f, a3 = 0.f;
            #pragma unroll
            for (int k = 0; k < 16; ++k) {
                const float w = qb[lane + 64 * k];
                a0 += w * E[k][0]; a1 += w * E[k][1];
                a2 += w * E[k][2]; a3 += w * E[k][3];
            }

            {   // split-reduction: 4 accs -> 1 per lane (row = cl)
                const bool h1 = lane & 1;
                float s0 = h1 ? a0 : a2;  float r0 = __shfl_xor(s0, 1, 64);
                float s1 = h1 ? a1 : a3;  float r1 = __shfl_xor(s1, 1, 64);
                a0 = (h1 ? a2 : a0) + r0;
                a1 = (h1 ? a3 : a1) + r1;
                const bool h2 = lane & 2;
                float s2 = h2 ? a0 : a1;  float r2 = __shfl_xor(s2, 2, 64);
                a0 = (h2 ? a1 : a0) + r2;
            }
            float sum = a0;
            sum += __shfl_xor(sum, 4, 64);
            sum += __shfl_xor(sum, 8, 64);
            sum += __shfl_xor(sum, 16, 64);
            sum += __shfl_xor(sum, 32, 64);

            const float nb = sb + __logf(sum);      // emission already inside w
            if (lane < 4) {
                const uint64_t pv2 = pack_su(s, nb);
                st2_sc0(&wX[rowbase + cl], pv2);
                st2_agent(&wA[rowbase + cl], pv2);
            }
            if (tid == 0) sh_shift = nb;
            __syncthreads();
        }
        return;
    }
}

// =====================================================================
// Fallback 1: proven agent-scope meet-in-the-middle (2270 us).
// Requires ws >= (4*L + 1) * 8 = 32776 bytes.
// =====================================================================
__global__ __launch_bounds__(TPB, 1)
void crf_mitm(const float* __restrict__ feats,
              const float* __restrict__ transfer,
              const int* __restrict__ target,
              float* __restrict__ out,
              uint64_t* __restrict__ ws64)
{
    __shared__ __align__(16) float qbuf[2][L];
    __shared__ float red[8];

    uint64_t* fb0 = ws64;
    uint64_t* fb1 = ws64 + L;
    uint64_t* bb0 = ws64 + 2 * L;
    uint64_t* bb1 = ws64 + 3 * L;
    uint64_t* goldslot = ws64 + 4 * L;

    const int b    = blockIdx.x;
    const int tid  = threadIdx.x;
    const int lane = tid & 63;
    const int wv   = tid >> 6;
    const int cl   = 2 * (lane & 1) + ((lane >> 1) & 1);

    if (b == GOLDB) {
        float s = 0.f;
        for (int t = tid; t < T_LEN; t += TPB)
            s += feats[t * L + target[t]];
        for (int t = tid; t < T_LEN - 1; t += TPB)
            s += transfer[target[t] * L + target[t + 1]];
        #pragma unroll
        for (int m = 32; m; m >>= 1) s += __shfl_xor(s, m, 64);
        if (lane == 0) red[wv] = s;
        __syncthreads();
        if (tid == 0) {
            float g = red[0] + red[1] + red[2] + red[3];
            STA(goldslot, pack_su(1, g));
        }
        return;
    }

    if (b < NFB) {
        const int gcb    = b * CPB + 4 * wv;
        const int shslot = b * CPB;

        float E[16][4];
        #pragma unroll
        for (int k = 0; k < 16; ++k) {
            const float4 r = *(const float4*)(transfer + (size_t)(lane + 64 * k) * L + gcb);
            E[k][0] = __expf(r.x); E[k][1] = __expf(r.y);
            E[k][2] = __expf(r.z); E[k][3] = __expf(r.w);
        }

        if (tid < CPB) {
            int j = b * CPB + tid;
            STA(&fb0[j], pack_su(0, feats[j]));
        }

        for (int t = 1; t <= TMID; ++t) {
            uint64_t* rbuf = (t & 1) ? fb0 : fb1;
            uint64_t* wbuf = (t & 1) ? fb1 : fb0;
            const int expect = t - 1;

            const float fe = feats[(size_t)t * L + gcb + cl];

            const uint64_t* rp = rbuf + 4 * tid;
            uint64_t v0, v1, v2, v3, vs;
            int n = 0;
            for (;;) {
                v0 = LDA(rp + 0); v1 = LDA(rp + 1);
                v2 = LDA(rp + 2); v3 = LDA(rp + 3);
                vs = LDA(rbuf + shslot);
                bool ready = ((int)(v0 >> 32) >= expect) & ((int)(v1 >> 32) >= expect) &
                             ((int)(v2 >> 32) >= expect) & ((int)(v3 >> 32) >= expect) &
                             ((int)(vs >> 32) >= expect);
                if (ready || ++n >= SPIN_MAX) break;
            }
            const float sloc = __uint_as_float((uint32_t)vs);

            float* qb = qbuf[t & 1];
            float4 qv;
            qv.x = __expf(__uint_as_float((uint32_t)v0) - sloc);
            qv.y = __expf(__uint_as_float((uint32_t)v1) - sloc);
            qv.z = __expf(__uint_as_float((uint32_t)v2) - sloc);
            qv.w = __expf(__uint_as_float((uint32_t)v3) - sloc);
            ((float4*)qb)[tid] = qv;
            __syncthreads();

            float a0 = 0.f, a1 = 0.f, a2 = 0.f, a3 = 0.f;
            #pragma unroll
            for (int k = 0; k < 16; ++k) {
                const float q = qb[lane + 64 * k];
                a0 += q * E[k][0]; a1 += q * E[k][1];
                a2 += q * E[k][2]; a3 += q * E[k][3];
            }

            {
                const bool h1 = lane & 1;
                float s0 = h1 ? a0 : a2;  float r0 = __shfl_xor(s0, 1, 64);
                float s1 = h1 ? a1 : a3;  float r1 = __shfl_xor(s1, 1, 64);
                a0 = (h1 ? a2 : a0) + r0;
                a1 = (h1 ? a3 : a1) + r1;
                const bool h2 = lane & 2;
                float s2 = h2 ? a0 : a1;  float r2 = __shfl_xor(s2, 2, 64);
                a0 = (h2 ? a1 : a0) + r2;
            }
            float s = a0;
            s += __shfl_xor(s, 4, 64);
            s += __shfl_xor(s, 8, 64);
            s += __shfl_xor(s, 16, 64);
            s += __shfl_xor(s, 32, 64);

            const float nv = sloc + __logf(s) + fe;
            if (lane < 4)
                STA(&wbuf[gcb + cl], pack_su(t, nv));
        }

        if (b == 0) {
            const uint64_t* fp = fb1 + 4 * tid;
            const uint64_t* bp = bb0 + 4 * tid;
            uint64_t f0, f1, f2, f3, g0, g1, g2, g3;
            int n = 0;
            for (;;) {
                f0 = LDA(fp + 0); f1 = LDA(fp + 1); f2 = LDA(fp + 2); f3 = LDA(fp + 3);
                g0 = LDA(bp + 0); g1 = LDA(bp + 1); g2 = LDA(bp + 2); g3 = LDA(bp + 3);
                bool ready = ((int)(f0 >> 32) >= TMID) & ((int)(f1 >> 32) >= TMID) &
                             ((int)(f2 >> 32) >= TMID) & ((int)(f3 >> 32) >= TMID) &
                             ((int)(g0 >> 32) >= BSTEPS) & ((int)(g1 >> 32) >= BSTEPS) &
                             ((int)(g2 >> 32) >= BSTEPS) & ((int)(g3 >> 32) >= BSTEPS);
                if (ready || ++n >= SPIN_MAX) break;
            }
            float sv[4] = {
                __uint_as_float((uint32_t)f0) + __uint_as_float((uint32_t)g0),
                __uint_as_float((uint32_t)f1) + __uint_as_float((uint32_t)g1),
                __uint_as_float((uint32_t)f2) + __uint_as_float((uint32_t)g2),
                __uint_as_float((uint32_t)f3) + __uint_as_float((uint32_t)g3) };
            float mx = fmaxf(fmaxf(sv[0], sv[1]), fmaxf(sv[2], sv[3]));
            #pragma unroll
            for (int m = 32; m; m >>= 1) mx = fmaxf(mx, __shfl_xor(mx, m, 64));
            if (lane == 0) red[wv] = mx;
            __syncthreads();
            const float M = fmaxf(fmaxf(red[0], red[1]), fmaxf(red[2], red[3]));
            float sm = 0.f;
            #pragma unroll
            for (int k = 0; k < 4; ++k) sm += __expf(sv[k] - M);
            #pragma unroll
            for (int m = 32; m; m >>= 1) sm += __shfl_xor(sm, m, 64);
            if (lane == 0) red[4 + wv] = sm;
            __syncthreads();
            if (tid == 0) {
                const float S = red[4] + red[5] + red[6] + red[7];
                const float lse = M + __logf(S);
                uint64_t g = LDA(goldslot);
                int n2 = 0;
                while ((int)(g >> 32) < 1 && ++n2 < SPIN_MAX) g = LDA(goldslot);
                out[0] = lse - __uint_as_float((uint32_t)g);
            }
        }
        return;
    }

    {
        const int rb      = b - NFB;
        const int rowbase = rb * CPB + 4 * wv;
        const int shslot  = rb * CPB;

        float E[16][4];
        #pragma unroll
        for (int r = 0; r < 4; ++r) {
            const float* rowp = transfer + (size_t)(rowbase + r) * L + lane;
            #pragma unroll
            for (int k = 0; k < 16; ++k)
                E[k][r] = __expf(rowp[64 * k]);
        }

        if (tid < CPB) {
            int j = rb * CPB + tid;
            STA(&bb0[j], pack_su(0, 0.f));
        }

        for (int s = 1; s <= BSTEPS; ++s) {
            uint64_t* rbuf = (s & 1) ? bb0 : bb1;
            uint64_t* wbuf = (s & 1) ? bb1 : bb0;
            const int expect = s - 1;
            const int t = T_LEN - s;

            const float4 fv = *(const float4*)(feats + (size_t)t * L + 4 * tid);

            const uint64_t* rp = rbuf + 4 * tid;
            uint64_t v0, v1, v2, v3, vs;
            int n = 0;
            for (;;) {
                v0 = LDA(rp + 0); v1 = LDA(rp + 1);
                v2 = LDA(rp + 2); v3 = LDA(rp + 3);
                vs = LDA(rbuf + shslot);
                bool ready = ((int)(v0 >> 32) >= expect) & ((int)(v1 >> 32) >= expect) &
                             ((int)(v2 >> 32) >= expect) & ((int)(v3 >> 32) >= expect) &
                             ((int)(vs >> 32) >= expect);
                if (ready || ++n >= SPIN_MAX) break;
            }
            const float sb = __uint_as_float((uint32_t)vs);

            float* qb = qbuf[s & 1];
            float4 wv4;
            wv4.x = __expf(fv.x + __uint_as_float((uint32_t)v0) - sb);
            wv4.y = __expf(fv.y + __uint_as_float((uint32_t)v1) - sb);
            wv4.z = __expf(fv.z + __uint_as_float((uint32_t)v2) - sb);
            wv4.w = __expf(fv.w + __uint_as_float((uint32_t)v3) - sb);
            ((float4*)qb)[tid] = wv4;
            __syncthreads();

            float a0 = 0.f, a1 = 0.f, a2 = 0.f, a3 = 0.f;
            #pragma unroll
            for (int k = 0; k < 16; ++k) {
                const float w = qb[lane + 64 * k];
                a0 += w * E[k][0]; a1 += w * E[k][1];
                a2 += w * E[k][2]; a3 += w * E[k][3];
            }

            {
                const bool h1 = lane & 1;
                float s0 = h1 ? a0 : a2;  float r0 = __shfl_xor(s0, 1, 64);
                float s1 = h1 ? a1 : a3;  float r1 = __shfl_xor(s1, 1, 64);
                a0 = (h1 ? a2 : a0) + r0;
                a1 = (h1 ? a3 : a1) + r1;
                const bool h2 = lane & 2;
                float s2 = h2 ? a0 : a1;  float r2 = __shfl_xor(s2, 2, 64);
                a0 = (h2 ? a1 : a0) + r2;
            }
            float sum = a0;
            sum += __shfl_xor(sum, 4, 64);
            sum += __shfl_xor(sum, 8, 64);
            sum += __shfl_xor(sum, 16, 64);
            sum += __shfl_xor(sum, 32, 64);

            const float nb = sb + __logf(sum);
            if (lane < 4)
                STA(&wbuf[rowbase + cl], pack_su(s, nb));
        }
    }
}

// =====================================================================
// Fallback 2: proven single-forward-chain kernel (4.16 ms).
// Requires only (2*L + 1) * 8 = 16392 bytes of ws.
// =====================================================================
__global__ __launch_bounds__(TPB, 1)
void crf_single(const float* __restrict__ feats,
                const float* __restrict__ transfer,
                const int* __restrict__ target,
                float* __restrict__ out,
                uint64_t* __restrict__ ws64)
{
    __shared__ __align__(16) float qbuf[2][L];
    __shared__ float red[8];

    uint64_t* buf0 = ws64;
    uint64_t* buf1 = ws64 + L;
    uint64_t* goldslot = ws64 + 2 * L;

    const int b   = blockIdx.x;
    const int tid = threadIdx.x;
    const int lane = tid & 63;
    const int wv   = tid >> 6;
    const int cl   = 2 * (lane & 1) + ((lane >> 1) & 1);

    if (b == NFB) {
        float s = 0.f;
        for (int t = tid; t < T_LEN; t += TPB)
            s += feats[t * L + target[t]];
        for (int t = tid; t < T_LEN - 1; t += TPB)
            s += transfer[target[t] * L + target[t + 1]];
        #pragma unroll
        for (int m = 32; m; m >>= 1) s += __shfl_xor(s, m, 64);
        if (lane == 0) red[wv] = s;
        __syncthreads();
        if (tid == 0) {
            float g = red[0] + red[1] + red[2] + red[3];
            STA(goldslot, pack_su(1, g));
        }
        return;
    }

    const int gcb    = b * CPB + 4 * wv;
    const int shslot = b * CPB;

    float E[16][4];
    #pragma unroll
    for (int k = 0; k < 16; ++k) {
        const float4 r = *(const float4*)(transfer + (size_t)(lane + 64 * k) * L + gcb);
        E[k][0] = __expf(r.x); E[k][1] = __expf(r.y);
        E[k][2] = __expf(r.z); E[k][3] = __expf(r.w);
    }

    if (tid < CPB) {
        int j = b * CPB + tid;
        STA(&buf0[j], pack_su(0, feats[j]));
    }

    for (int t = 1; t < T_LEN; ++t) {
        uint64_t* rbuf = (t & 1) ? buf0 : buf1;
        uint64_t* wbuf = (t & 1) ? buf1 : buf0;
        const int expect = t - 1;
        const float fe = feats[(size_t)t * L + gcb + cl];

        const uint64_t* rp = rbuf + 4 * tid;
        uint64_t v0, v1, v2, v3, vs;
        int n = 0;
        for (;;) {
            v0 = LDA(rp + 0); v1 = LDA(rp + 1);
            v2 = LDA(rp + 2); v3 = LDA(rp + 3);
            vs = LDA(rbuf + shslot);
            bool ready = ((int)(v0 >> 32) >= expect) & ((int)(v1 >> 32) >= expect) &
                         ((int)(v2 >> 32) >= expect) & ((int)(v3 >> 32) >= expect) &
                         ((int)(vs >> 32) >= expect);
            if (ready || ++n >= SPIN_MAX) break;
        }
        const float sloc = __uint_as_float((uint32_t)vs);

        float* qb = qbuf[t & 1];
        float4 qv;
        qv.x = __expf(__uint_as_float((uint32_t)v0) - sloc);
        qv.y = __expf(__uint_as_float((uint32_t)v1) - sloc);
        qv.z = __expf(__uint_as_float((uint32_t)v2) - sloc);
        qv.w = __expf(__uint_as_float((uint32_t)v3) - sloc);
        ((float4*)qb)[tid] = qv;
        __syncthreads();

        float a0 = 0.f, a1 = 0.f, a2 = 0.f, a3 = 0.f;
        #pragma unroll
        for (int k = 0; k < 16; ++k) {
            const float q = qb[lane + 64 * k];
            a0 += q * E[k][0]; a1 += q * E[k][1];
            a2 += q * E[k][2]; a3 += q * E[k][3];
        }
        {
            const bool h1 = lane & 1;
            float s0 = h1 ? a0 : a2;  float r0 = __shfl_xor(s0, 1, 64);
            float s1 = h1 ? a1 : a3;  float r1 = __shfl_xor(s1, 1, 64);
            a0 = (h1 ? a2 : a0) + r0;
            a1 = (h1 ? a3 : a1) + r1;
            const bool h2 = lane & 2;
            float s2 = h2 ? a0 : a1;  float r2 = __shfl_xor(s2, 2, 64);
            a0 = (h2 ? a1 : a0) + r2;
        }
        float s = a0;
        s += __shfl_xor(s, 4, 64);
        s += __shfl_xor(s, 8, 64);
        s += __shfl_xor(s, 16, 64);
        s += __shfl_xor(s, 32, 64);

        const float nv = sloc + __logf(s) + fe;
        if (lane < 4)
            STA(&wbuf[gcb + cl], pack_su(t, nv));
    }

    if (b == 0) {
        const uint64_t* fp = buf1 + 4 * tid;
        uint64_t v0, v1, v2, v3;
        int n = 0;
        for (;;) {
            v0 = LDA(fp + 0); v1 = LDA(fp + 1);
            v2 = LDA(fp + 2); v3 = LDA(fp + 3);
            bool ready = ((int)(v0 >> 32) >= T_LEN - 1) & ((int)(v1 >> 32) >= T_LEN - 1) &
                         ((int)(v2 >> 32) >= T_LEN - 1) & ((int)(v3 >> 32) >= T_LEN - 1);
            if (ready || ++n >= SPIN_MAX) break;
        }
        float sv[4] = { __uint_as_float((uint32_t)v0), __uint_as_float((uint32_t)v1),
                        __uint_as_float((uint32_t)v2), __uint_as_float((uint32_t)v3) };
        float mx = fmaxf(fmaxf(sv[0], sv[1]), fmaxf(sv[2], sv[3]));
        #pragma unroll
        for (int m = 32; m; m >>= 1) mx = fmaxf(mx, __shfl_xor(mx, m, 64));
        if (lane == 0) red[wv] = mx;
        __syncthreads();
        const float M = fmaxf(fmaxf(red[0], red[1]), fmaxf(red[2], red[3]));
        float sm = 0.f;
        #pragma unroll
        for (int k = 0; k < 4; ++k) sm += __expf(sv[k] - M);
        #pragma unroll
        for (int m = 32; m; m >>= 1) sm += __shfl_xor(sm, m, 64);
        if (lane == 0) red[4 + wv] = sm;
        __syncthreads();
        if (tid == 0) {
            const float S = red[4] + red[5] + red[6] + red[7];
            const float lse = M + __logf(S);
            uint64_t g = LDA(goldslot);
            int n2 = 0;
            while ((int)(g >> 32) < 1 && ++n2 < SPIN_MAX) g = LDA(goldslot);
            out[0] = lse - __uint_as_float((uint32_t)g);
        }
    }
}

extern "C" void kernel_launch(void* const* d_in, const int* in_sizes, int n_in,
                              void* d_out, int out_size, void* d_ws, size_t ws_size,
                              hipStream_t stream) {
    const float* feats    = (const float*)d_in[0];
    const float* transfer = (const float*)d_in[1];
    const int*   target   = (const int*)d_in[2];
    float* out = (float*)d_out;
    uint64_t* ws64 = (uint64_t*)d_ws;

    if (ws_size >= (8 * L + 1) * sizeof(uint64_t)) {
        // dual-published MITM: sc0 fast path + agent ground truth, adaptive
        hipLaunchKernelGGL(crf_v3, dim3(V3_GRID), dim3(TPB), 0, stream,
                           feats, transfer, target, out, ws64);
    } else if (ws_size >= (4 * L + 1) * sizeof(uint64_t)) {
        // proven agent-scope meet-in-the-middle (2270 us)
        hipLaunchKernelGGL(crf_mitm, dim3(GOLDB + 1), dim3(TPB), 0, stream,
                           feats, transfer, target, out, ws64);
    } else {
        // proven single-chain fallback (R4): needs only 16392 B of ws
        hipLaunchKernelGGL(crf_single, dim3(NFB + 1), dim3(TPB), 0, stream,
                           feats, transfer, target, out, ws64);
    }
}

// Round 4
// 1678.807 us; speedup vs baseline: 2.2765x; 2.2765x over previous
//
#include <hip/hip_runtime.h>
#include <stdint.h>

#define T_LEN 2048
#define L     1024
#define TPBW  1024          // wide block: 16 waves, 64 columns (4 per wave)
#define NCB   16            // chain blocks per direction
#define COLS  64            // columns (rows) per block
#define GOLDW 32            // gold block id in v4 grid
#define TMID  1023          // forward computes f_{1023}; backward computes b_{1023}
#define BSTEPS 1024         // backward step count (s=1..1024, emission row t=2048-s)
#define SPIN_MAX (1 << 14)  // bounded: wedge exits, normal use 1-3 iters

// legacy fallback geometry
#define NFB   64
#define CPB   16
#define TPB   256

#define SCOPE_AGENT __HIP_MEMORY_SCOPE_AGENT
#define LDA(p) __hip_atomic_load((p), __ATOMIC_RELAXED, SCOPE_AGENT)
#define STA(p, v) __hip_atomic_store((p), (v), __ATOMIC_RELAXED, SCOPE_AGENT)

__device__ __forceinline__ uint64_t pack_su(int tag, float v) {
    return ((uint64_t)(uint32_t)tag << 32) | (uint64_t)__float_as_uint(v);
}

// =====================================================================
// v4: wide-block meet-in-the-middle (agent scope only, no placement
// assumptions).  16 fwd blocks + 16 bwd blocks + 1 gold, 1024 thr each.
//   - per-step handoff = max over 16 writers (was 64): less skew
//   - each thread polls exactly ONE u64 slot (was 4 + shift): less UC
//     contention, fewer poll iterations
//   - exp-shift is block-local (own previous value via LDS broadcast):
//     no cross-block shift dependency
//   - step 1 reads inputs directly: no seed stores; same ws assumption
//     as the proven baseline (initial tags <= 0)
// ws layout (u64): fb0[L](unused) fb1[L] bb0[L] bb1[L] gold
// Requires ws >= (4*L + 1) * 8 = 32776 bytes.
// =====================================================================
__global__ __launch_bounds__(TPBW, 1)
void crf_v4(const float* __restrict__ feats,
            const float* __restrict__ transfer,
            const int* __restrict__ target,
            float* __restrict__ out,
            uint64_t* __restrict__ ws64)
{
    __shared__ __align__(16) float qbuf[2][L];      // 8 KB, double-buffered
    __shared__ float red[32];                        // [0..15] max, [16..31] sum
    __shared__ float sh_shift;

    uint64_t* fb0 = ws64;                            // kept for layout (unused)
    uint64_t* fb1 = ws64 + L;
    uint64_t* bb0 = ws64 + 2 * L;
    uint64_t* bb1 = ws64 + 3 * L;
    uint64_t* goldslot = ws64 + 4 * L;
    (void)fb0;

    const int bid  = blockIdx.x;
    const int tid  = threadIdx.x;                    // 0..1023
    const int lane = tid & 63;
    const int wv   = tid >> 6;                       // wave 0..15
    const int cl   = 2 * (lane & 1) + ((lane >> 1) & 1);   // bijective on lanes 0..3

    // ---------------- gold block ----------------
    if (bid == GOLDW) {
        float s = 0.f;
        for (int t = tid; t < T_LEN; t += TPBW)
            s += feats[t * L + target[t]];
        for (int t = tid; t < T_LEN - 1; t += TPBW)
            s += transfer[target[t] * L + target[t + 1]];
        #pragma unroll
        for (int m = 32; m; m >>= 1) s += __shfl_xor(s, m, 64);
        if (lane == 0) red[wv] = s;
        __syncthreads();
        if (tid == 0) {
            float g = 0.f;
            #pragma unroll
            for (int i = 0; i < 16; ++i) g += red[i];
            STA(goldslot, pack_su(1, g));
        }
        return;
    }

    if (bid < NCB) {
        // ================= FORWARD chain (16 blocks, 1023 steps) =================
        const int role    = bid;
        const int colbase = role * COLS;
        const int gcb     = colbase + 4 * wv;        // wave's first global column

        float E[16][4];                              // E[k][c]=exp(transfer[lane+64k][gcb+c])
        #pragma unroll
        for (int k = 0; k < 16; ++k) {
            const float4 r = *(const float4*)(transfer + (size_t)(lane + 64 * k) * L + gcb);
            E[k][0] = __expf(r.x); E[k][1] = __expf(r.y);
            E[k][2] = __expf(r.z); E[k][3] = __expf(r.w);
        }

        for (int t = 1; t <= TMID; ++t) {
            const int par = t & 1;
            const uint64_t* rbuf = par ? fb0 : fb1;  // written at t-1
            uint64_t* wbuf = par ? fb1 : fb0;
            const int expect = t - 1;

            const float fe = feats[(size_t)t * L + gcb + cl];   // overlaps poll

            float val, sloc;
            if (t == 1) {
                val  = feats[tid];                   // f_0 = feats[0][tid], direct
                sloc = feats[colbase];
            } else {
                sloc = sh_shift;                     // own previous value (post-barrier)
                const uint64_t* p = rbuf + tid;      // ONE slot per thread
                uint64_t v;
                int n = 0;
                do { v = LDA(p); } while ((int)(v >> 32) < expect && ++n < SPIN_MAX);
                val = __uint_as_float((uint32_t)v);
            }

            float* qb = qbuf[par];
            qb[tid] = __expf(val - sloc);
            __syncthreads();

            float a0 = 0.f, a1 = 0.f, a2 = 0.f, a3 = 0.f;
            #pragma unroll
            for (int k = 0; k < 16; ++k) {
                const float q = qb[lane + 64 * k];   // conflict-free ds_read_b32
                a0 += q * E[k][0]; a1 += q * E[k][1];
                a2 += q * E[k][2]; a3 += q * E[k][3];
            }

            {   // split-reduction: 4 accs -> 1 per lane (col = cl)
                const bool h1 = lane & 1;
                float s0 = h1 ? a0 : a2;  float r0 = __shfl_xor(s0, 1, 64);
                float s1 = h1 ? a1 : a3;  float r1 = __shfl_xor(s1, 1, 64);
                a0 = (h1 ? a2 : a0) + r0;
                a1 = (h1 ? a3 : a1) + r1;
                const bool h2 = lane & 2;
                float s2 = h2 ? a0 : a1;  float r2 = __shfl_xor(s2, 2, 64);
                a0 = (h2 ? a1 : a0) + r2;
            }
            float s = a0;
            s += __shfl_xor(s, 4, 64);
            s += __shfl_xor(s, 8, 64);
            s += __shfl_xor(s, 16, 64);
            s += __shfl_xor(s, 32, 64);

            const float nv = sloc + __logf(s) + fe;
            if (lane < 4)
                STA(&wbuf[gcb + cl], pack_su(t, nv));
            if (tid == 0) sh_shift = nv;             // col colbase value
            __syncthreads();                         // protects sh_shift
        }

        // ---------- role 0: logZ = lse(f_{1023} + b_{1023}) - gold ----------
        if (role == 0) {
            const uint64_t* fp = fb1 + tid;          // t=1023 odd -> fb1
            const uint64_t* bp = bb0 + tid;          // s=1024 even -> bb0
            uint64_t fv_, bv_;
            int n = 0;
            for (;;) {
                fv_ = LDA(fp); bv_ = LDA(bp);
                bool ready = ((int)(fv_ >> 32) >= TMID) & ((int)(bv_ >> 32) >= BSTEPS);
                if (ready || ++n >= SPIN_MAX) break;
            }
            const float sv = __uint_as_float((uint32_t)fv_) + __uint_as_float((uint32_t)bv_);
            float mx = sv;
            #pragma unroll
            for (int m = 32; m; m >>= 1) mx = fmaxf(mx, __shfl_xor(mx, m, 64));
            if (lane == 0) red[wv] = mx;
            __syncthreads();
            float M = red[0];
            #pragma unroll
            for (int i = 1; i < 16; ++i) M = fmaxf(M, red[i]);
            float sm = __expf(sv - M);
            #pragma unroll
            for (int m = 32; m; m >>= 1) sm += __shfl_xor(sm, m, 64);
            if (lane == 0) red[16 + wv] = sm;
            __syncthreads();
            if (tid == 0) {
                float S = 0.f;
                #pragma unroll
                for (int i = 0; i < 16; ++i) S += red[16 + i];
                const float lse = M + __logf(S);
                uint64_t g = LDA(goldslot);
                int n2 = 0;
                while ((int)(g >> 32) < 1 && ++n2 < SPIN_MAX) g = LDA(goldslot);
                out[0] = lse - __uint_as_float((uint32_t)g);
            }
        }
        return;
    }

    if (bid < 2 * NCB) {
        // ================= BACKWARD chain (16 blocks, 1024 steps) =================
        const int role    = bid - NCB;
        const int rowbase = role * COLS + 4 * wv;    // wave's first global row

        // E[k][r] = exp(transfer[(rowbase+r)*L + lane+64k]) — coalesced staging
        float E[16][4];
        #pragma unroll
        for (int r = 0; r < 4; ++r) {
            const float* rowp = transfer + (size_t)(rowbase + r) * L + lane;
            #pragma unroll
            for (int k = 0; k < 16; ++k)
                E[k][r] = __expf(rowp[64 * k]);
        }

        for (int s = 1; s <= BSTEPS; ++s) {
            const int par = s & 1;
            const uint64_t* rbuf = par ? bb0 : bb1;
            uint64_t* wbuf = par ? bb1 : bb0;
            const int expect = s - 1;
            const int t = T_LEN - s;                 // emission row for this step

            const float fvv = feats[(size_t)t * L + tid];   // overlaps poll

            float bval, sb;
            if (s == 1) {
                bval = 0.f; sb = 0.f;                // b_{2047} = 0
            } else {
                sb = sh_shift;
                const uint64_t* p = rbuf + tid;      // ONE slot per thread
                uint64_t v;
                int n = 0;
                do { v = LDA(p); } while ((int)(v >> 32) < expect && ++n < SPIN_MAX);
                bval = __uint_as_float((uint32_t)v);
            }

            // w_j = exp(feats[t][j] + b[j] - sb) -> LDS broadcast
            float* qb = qbuf[par];
            qb[tid] = __expf(fvv + bval - sb);
            __syncthreads();

            // matvec: acc[r] += w[lane+64k] * E[k][r]
            float a0 = 0.f, a1 = 0.f, a2 = 0.f, a3 = 0.f;
            #pragma unroll
            for (int k = 0; k < 16; ++k) {
                const float w = qb[lane + 64 * k];
                a0 += w * E[k][0]; a1 += w * E[k][1];
                a2 += w * E[k][2]; a3 += w * E[k][3];
            }

            {   // split-reduction: 4 accs -> 1 per lane (row = cl)
                const bool h1 = lane & 1;
                float s0 = h1 ? a0 : a2;  float r0 = __shfl_xor(s0, 1, 64);
                float s1 = h1 ? a1 : a3;  float r1 = __shfl_xor(s1, 1, 64);
                a0 = (h1 ? a2 : a0) + r0;
                a1 = (h1 ? a3 : a1) + r1;
                const bool h2 = lane & 2;
                float s2 = h2 ? a0 : a1;  float r2 = __shfl_xor(s2, 2, 64);
                a0 = (h2 ? a1 : a0) + r2;
            }
            float sum = a0;
            sum += __shfl_xor(sum, 4, 64);
            sum += __shfl_xor(sum, 8, 64);
            sum += __shfl_xor(sum, 16, 64);
            sum += __shfl_xor(sum, 32, 64);

            const float nb = sb + __logf(sum);       // emission already inside w
            if (lane < 4)
                STA(&wbuf[rowbase + cl], pack_su(s, nb));
            if (tid == 0) sh_shift = nb;
            __syncthreads();
        }
        return;
    }
    // bid in (2*NCB, GOLDW): none launched
}

// =====================================================================
// Fallback: proven single-forward-chain kernel (4.16 ms).
// Requires only (2*L + 1) * 8 = 16392 bytes of ws.
// =====================================================================
__global__ __launch_bounds__(TPB, 1)
void crf_single(const float* __restrict__ feats,
                const float* __restrict__ transfer,
                const int* __restrict__ target,
                float* __restrict__ out,
                uint64_t* __restrict__ ws64)
{
    __shared__ __align__(16) float qbuf[2][L];
    __shared__ float red[8];

    uint64_t* buf0 = ws64;
    uint64_t* buf1 = ws64 + L;
    uint64_t* goldslot = ws64 + 2 * L;

    const int b   = blockIdx.x;
    const int tid = threadIdx.x;
    const int lane = tid & 63;
    const int wv   = tid >> 6;
    const int cl   = 2 * (lane & 1) + ((lane >> 1) & 1);

    if (b == NFB) {
        float s = 0.f;
        for (int t = tid; t < T_LEN; t += TPB)
            s += feats[t * L + target[t]];
        for (int t = tid; t < T_LEN - 1; t += TPB)
            s += transfer[target[t] * L + target[t + 1]];
        #pragma unroll
        for (int m = 32; m; m >>= 1) s += __shfl_xor(s, m, 64);
        if (lane == 0) red[wv] = s;
        __syncthreads();
        if (tid == 0) {
            float g = red[0] + red[1] + red[2] + red[3];
            STA(goldslot, pack_su(1, g));
        }
        return;
    }

    const int gcb    = b * CPB + 4 * wv;
    const int shslot = b * CPB;

    float E[16][4];
    #pragma unroll
    for (int k = 0; k < 16; ++k) {
        const float4 r = *(const float4*)(transfer + (size_t)(lane + 64 * k) * L + gcb);
        E[k][0] = __expf(r.x); E[k][1] = __expf(r.y);
        E[k][2] = __expf(r.z); E[k][3] = __expf(r.w);
    }

    if (tid < CPB) {
        int j = b * CPB + tid;
        STA(&buf0[j], pack_su(0, feats[j]));
    }

    for (int t = 1; t < T_LEN; ++t) {
        uint64_t* rbuf = (t & 1) ? buf0 : buf1;
        uint64_t* wbuf = (t & 1) ? buf1 : buf0;
        const int expect = t - 1;
        const float fe = feats[(size_t)t * L + gcb + cl];

        const uint64_t* rp = rbuf + 4 * tid;
        uint64_t v0, v1, v2, v3, vs;
        int n = 0;
        for (;;) {
            v0 = LDA(rp + 0); v1 = LDA(rp + 1);
            v2 = LDA(rp + 2); v3 = LDA(rp + 3);
            vs = LDA(rbuf + shslot);
            bool ready = ((int)(v0 >> 32) >= expect) & ((int)(v1 >> 32) >= expect) &
                         ((int)(v2 >> 32) >= expect) & ((int)(v3 >> 32) >= expect) &
                         ((int)(vs >> 32) >= expect);
            if (ready || ++n >= SPIN_MAX) break;
        }
        const float sloc = __uint_as_float((uint32_t)vs);

        float* qb = qbuf[t & 1];
        float4 qv;
        qv.x = __expf(__uint_as_float((uint32_t)v0) - sloc);
        qv.y = __expf(__uint_as_float((uint32_t)v1) - sloc);
        qv.z = __expf(__uint_as_float((uint32_t)v2) - sloc);
        qv.w = __expf(__uint_as_float((uint32_t)v3) - sloc);
        ((float4*)qb)[tid] = qv;
        __syncthreads();

        float a0 = 0.f, a1 = 0.f, a2 = 0.f, a3 = 0.f;
        #pragma unroll
        for (int k = 0; k < 16; ++k) {
            const float q = qb[lane + 64 * k];
            a0 += q * E[k][0]; a1 += q * E[k][1];
            a2 += q * E[k][2]; a3 += q * E[k][3];
        }
        {
            const bool h1 = lane & 1;
            float s0 = h1 ? a0 : a2;  float r0 = __shfl_xor(s0, 1, 64);
            float s1 = h1 ? a1 : a3;  float r1 = __shfl_xor(s1, 1, 64);
            a0 = (h1 ? a2 : a0) + r0;
            a1 = (h1 ? a3 : a1) + r1;
            const bool h2 = lane & 2;
            float s2 = h2 ? a0 : a1;  float r2 = __shfl_xor(s2, 2, 64);
            a0 = (h2 ? a1 : a0) + r2;
        }
        float s = a0;
        s += __shfl_xor(s, 4, 64);
        s += __shfl_xor(s, 8, 64);
        s += __shfl_xor(s, 16, 64);
        s += __shfl_xor(s, 32, 64);

        const float nv = sloc + __logf(s) + fe;
        if (lane < 4)
            STA(&wbuf[gcb + cl], pack_su(t, nv));
    }

    if (b == 0) {
        const uint64_t* fp = buf1 + 4 * tid;
        uint64_t v0, v1, v2, v3;
        int n = 0;
        for (;;) {
            v0 = LDA(fp + 0); v1 = LDA(fp + 1);
            v2 = LDA(fp + 2); v3 = LDA(fp + 3);
            bool ready = ((int)(v0 >> 32) >= T_LEN - 1) & ((int)(v1 >> 32) >= T_LEN - 1) &
                         ((int)(v2 >> 32) >= T_LEN - 1) & ((int)(v3 >> 32) >= T_LEN - 1);
            if (ready || ++n >= SPIN_MAX) break;
        }
        float sv[4] = { __uint_as_float((uint32_t)v0), __uint_as_float((uint32_t)v1),
                        __uint_as_float((uint32_t)v2), __uint_as_float((uint32_t)v3) };
        float mx = fmaxf(fmaxf(sv[0], sv[1]), fmaxf(sv[2], sv[3]));
        #pragma unroll
        for (int m = 32; m; m >>= 1) mx = fmaxf(mx, __shfl_xor(mx, m, 64));
        if (lane == 0) red[wv] = mx;
        __syncthreads();
        const float M = fmaxf(fmaxf(red[0], red[1]), fmaxf(red[2], red[3]));
        float sm = 0.f;
        #pragma unroll
        for (int k = 0; k < 4; ++k) sm += __expf(sv[k] - M);
        #pragma unroll
        for (int m = 32; m; m >>= 1) sm += __shfl_xor(sm, m, 64);
        if (lane == 0) red[4 + wv] = sm;
        __syncthreads();
        if (tid == 0) {
            const float S = red[4] + red[5] + red[6] + red[7];
            const float lse = M + __logf(S);
            uint64_t g = LDA(goldslot);
            int n2 = 0;
            while ((int)(g >> 32) < 1 && ++n2 < SPIN_MAX) g = LDA(goldslot);
            out[0] = lse - __uint_as_float((uint32_t)g);
        }
    }
}

extern "C" void kernel_launch(void* const* d_in, const int* in_sizes, int n_in,
                              void* d_out, int out_size, void* d_ws, size_t ws_size,
                              hipStream_t stream) {
    const float* feats    = (const float*)d_in[0];
    const float* transfer = (const float*)d_in[1];
    const int*   target   = (const int*)d_in[2];
    float* out = (float*)d_out;
    uint64_t* ws64 = (uint64_t*)d_ws;

    if (ws_size >= (4 * L + 1) * sizeof(uint64_t)) {
        // wide-block MITM: 16+16 writer blocks, 1-slot polls, agent scope
        hipLaunchKernelGGL(crf_v4, dim3(GOLDW + 1), dim3(TPBW), 0, stream,
                           feats, transfer, target, out, ws64);
    } else {
        // proven single-chain fallback (R4): needs only 16392 B of ws
        hipLaunchKernelGGL(crf_single, dim3(NFB + 1), dim3(TPB), 0, stream,
                           feats, transfer, target, out, ws64);
    }
}